// Round 6
// baseline (670.620 us; speedup 1.0000x reference)
//
#include <hip/hip_runtime.h>

// MHSA: B=32, C=512, HEADS=8, d=64, N=784. fp32 in/out.
// Round 14: attn occupancy unlock. pt (18.4KB LDS) removed — P routed from
// softmax regs to PV B-frags via in-register bf16x2 pack + 16 bpermute/chunk
// (wave-private quad permutation; map: js=(joff>>4)+(qt>>1),
// src=m+16*((qt&1)*2+(w>>1)), word=w&1; two pulls + select since qt and qt+2
// pull different js from the same source lane). LDS 62464->44032 B ->
// 3 blocks/CU (24 waves vs 16). __launch_bounds__(512,6) caps VGPR at 85.
// S-phase/softmax/staging/proj identical to R13 (passed, absmax 0.03125).

#define BATCH 32
#define CCH   512
#define NHEAD 8
#define DH    64
#define NTOK  784
#define WSP   28
#define OT    128    // proj o-tile
#define NT    112    // proj n-tile
#define WLD   40     // proj LDS row stride (u16)
#define CH    64     // attn j-chunk
#define NCHUNK 13
#define NIBLK  7     // ceil(784/128)
#define KQLD  136    // 128 + 8 pad (16B-mult)
#define VLD   72     // 64 + 8 pad (16B-mult)

typedef unsigned short u16;
typedef unsigned int   u32;
typedef short  short8  __attribute__((ext_vector_type(8)));
typedef float  floatx4 __attribute__((ext_vector_type(4)));

__device__ __forceinline__ u16 f2bf(float f) {
    union { float f; u32 i; } v; v.f = f;
    u32 x = v.i;
    return (u16)((x + 0x7FFFu + ((x >> 16) & 1u)) >> 16);
}
__device__ __forceinline__ u32 f2u(float f) { union { float f; u32 i; } v; v.f = f; return v.i; }
__device__ __forceinline__ float u2f(u32 u) { union { u32 i; float f; } v; v.i = u; return v.f; }

__device__ __forceinline__ u32 packsplit(float f) {
    const u32 hib = f2u(f) & 0xFFFF0000u;
    const float lo = f - u2f(hib);
    return ((u32)f2bf(lo) << 16) | (hib >> 16);
}

// ---------------- prepack: weights ----------------
__global__ __launch_bounds__(256)
void pack_weights(const float* __restrict__ wq, const float* __restrict__ wk,
                  const float* __restrict__ wv,
                  u32* __restrict__ Wqp, u32* __restrict__ Wkp, u32* __restrict__ Wvp)
{
    const int i = blockIdx.x * 256 + threadIdx.x;
    if (i < CCH * CCH) {
        Wqp[i] = packsplit(wq[i]);
        Wkp[i] = packsplit(wk[i]);
        Wvp[i] = packsplit(wv[i]);
    }
}

// ---------------- prepack: x transpose -> Xt[b][n][c] (packed hi|lo) ----------------
__global__ __launch_bounds__(256)
void pack_xt(const float* __restrict__ x, u32* __restrict__ Xt, int b0)
{
    const int bl = blockIdx.z;
    const int c0 = blockIdx.y * 32;
    const int n0 = blockIdx.x * 32;
    const int t  = threadIdx.x;
    const int tn = t & 31;          // 0..31
    const int tr = t >> 5;          // 0..7

    __shared__ float tile[32][33];

    const size_t xb = (size_t)(b0 + bl) * CCH * NTOK;
    #pragma unroll
    for (int k = 0; k < 4; k++) {
        const int c = tr + k * 8;                 // 0..31
        const int n = n0 + tn;
        if (n < NTOK)
            tile[c][tn] = x[xb + (size_t)(c0 + c) * NTOK + n];
    }
    __syncthreads();
    const size_t ob = (size_t)bl * NTOK * CCH;
    #pragma unroll
    for (int k = 0; k < 4; k++) {
        const int n = n0 + tr + k * 8;
        const int c = c0 + tn;
        if (n < NTOK)
            Xt[ob + (size_t)n * CCH + c] = packsplit(tile[tn][tr + k * 8]);
    }
}

// ---------------- MFMA QKV projection: 512 thr, o-tile 128 x n-tile 112 ----------------
__global__ __launch_bounds__(512, 4)
void qkv_proj(const u32* __restrict__ Xt,
              const u32* __restrict__ Wqp, const float* __restrict__ bq,
              const u32* __restrict__ Wkp, const float* __restrict__ bk,
              const u32* __restrict__ Wvp, const float* __restrict__ bv,
              u32* __restrict__ Qp, u32* __restrict__ Kp, u16* __restrict__ Vo,
              int nbatch)
{
    const int t    = threadIdx.x;
    const int lane = t & 63;
    const int wid  = t >> 6;        // 0..7
    const int z    = blockIdx.z;
    const int proj = z / nbatch;
    const int bl   = z - proj * nbatch;
    const int o0   = blockIdx.y * OT;     // y in 0..3
    const int n0   = blockIdx.x * NT;     // x in 0..6

    const u32*   Wp   = (proj == 0) ? Wqp : (proj == 1) ? Wkp : Wvp;
    const float* bias = (proj == 0) ? bq  : (proj == 1) ? bk  : bv;
    const bool   isV  = (proj == 2);      // block-uniform

    __shared__ u16 wh[OT][WLD], wl[OT][WLD];   // 2 x 10240 B
    __shared__ u16 xh[NT][WLD], xl[NT][WLD];   // 2 x 8960 B  (38400 total)

    const int m    = lane & 15;
    const int quad = lane >> 4;

    floatx4 acc[7];
    #pragma unroll
    for (int j = 0; j < 7; j++) acc[j] = (floatx4){0.f, 0.f, 0.f, 0.f};

    // staging maps: W by all 512 (128 rows x 8 u32), X by t<448 (112 rows x 8 u32)
    const int wo = t >> 2;           // 0..127
    const int wc = (t & 3) * 8;      // 0,8,16,24
    const int xrow = t >> 2;         // 0..111 (t<448)
    const int xc8  = (t & 3) * 8;    // 0,8,16,24

    const size_t xtbase = (size_t)bl * NTOK * CCH;

    // ---- prologue: load K-step 0 into regs
    uint4 wv0, wv1, xv0, xv1;
    {
        wv0 = *reinterpret_cast<const uint4*>(&Wp[(size_t)(o0 + wo) * CCH + 0 + wc]);
        wv1 = *reinterpret_cast<const uint4*>(&Wp[(size_t)(o0 + wo) * CCH + 0 + wc + 4]);
        if (t < 448) {
            xv0 = *reinterpret_cast<const uint4*>(&Xt[xtbase + (size_t)(n0 + xrow) * CCH + 0 + xc8]);
            xv1 = *reinterpret_cast<const uint4*>(&Xt[xtbase + (size_t)(n0 + xrow) * CCH + 0 + xc8 + 4]);
        }
    }

    for (int c0 = 0; c0 < CCH; c0 += 32) {
        __syncthreads();   // release: prev compute done
        {
            const u32 wr[8] = {wv0.x, wv0.y, wv0.z, wv0.w, wv1.x, wv1.y, wv1.z, wv1.w};
            ushort4 h0 = make_ushort4((u16)(wr[0] & 0xFFFF), (u16)(wr[1] & 0xFFFF), (u16)(wr[2] & 0xFFFF), (u16)(wr[3] & 0xFFFF));
            ushort4 h1 = make_ushort4((u16)(wr[4] & 0xFFFF), (u16)(wr[5] & 0xFFFF), (u16)(wr[6] & 0xFFFF), (u16)(wr[7] & 0xFFFF));
            *reinterpret_cast<ushort4*>(&wh[wo][wc])     = h0;
            *reinterpret_cast<ushort4*>(&wh[wo][wc + 4]) = h1;
            if (!isV) {
                ushort4 l0 = make_ushort4((u16)(wr[0] >> 16), (u16)(wr[1] >> 16), (u16)(wr[2] >> 16), (u16)(wr[3] >> 16));
                ushort4 l1 = make_ushort4((u16)(wr[4] >> 16), (u16)(wr[5] >> 16), (u16)(wr[6] >> 16), (u16)(wr[7] >> 16));
                *reinterpret_cast<ushort4*>(&wl[wo][wc])     = l0;
                *reinterpret_cast<ushort4*>(&wl[wo][wc + 4]) = l1;
            }
        }
        if (t < 448) {
            const u32 xr[8] = {xv0.x, xv0.y, xv0.z, xv0.w, xv1.x, xv1.y, xv1.z, xv1.w};
            ushort4 h0 = make_ushort4((u16)(xr[0] & 0xFFFF), (u16)(xr[1] & 0xFFFF), (u16)(xr[2] & 0xFFFF), (u16)(xr[3] & 0xFFFF));
            ushort4 h1 = make_ushort4((u16)(xr[4] & 0xFFFF), (u16)(xr[5] & 0xFFFF), (u16)(xr[6] & 0xFFFF), (u16)(xr[7] & 0xFFFF));
            ushort4 l0 = make_ushort4((u16)(xr[0] >> 16), (u16)(xr[1] >> 16), (u16)(xr[2] >> 16), (u16)(xr[3] >> 16));
            ushort4 l1 = make_ushort4((u16)(xr[4] >> 16), (u16)(xr[5] >> 16), (u16)(xr[6] >> 16), (u16)(xr[7] >> 16));
            *reinterpret_cast<ushort4*>(&xh[xrow][xc8])     = h0;
            *reinterpret_cast<ushort4*>(&xh[xrow][xc8 + 4]) = h1;
            *reinterpret_cast<ushort4*>(&xl[xrow][xc8])     = l0;
            *reinterpret_cast<ushort4*>(&xl[xrow][xc8 + 4]) = l1;
        }
        __syncthreads();   // publish

        // ---- prefetch next K-step; consumed next iteration
        if (c0 + 32 < CCH) {
            wv0 = *reinterpret_cast<const uint4*>(&Wp[(size_t)(o0 + wo) * CCH + c0 + 32 + wc]);
            wv1 = *reinterpret_cast<const uint4*>(&Wp[(size_t)(o0 + wo) * CCH + c0 + 32 + wc + 4]);
            if (t < 448) {
                xv0 = *reinterpret_cast<const uint4*>(&Xt[xtbase + (size_t)(n0 + xrow) * CCH + c0 + 32 + xc8]);
                xv1 = *reinterpret_cast<const uint4*>(&Xt[xtbase + (size_t)(n0 + xrow) * CCH + c0 + 32 + xc8 + 4]);
            }
        }
        __builtin_amdgcn_sched_barrier(0);   // keep load issue ahead of compute

        const short8 Ah = *reinterpret_cast<const short8*>(&wh[wid * 16 + m][quad * 8]);
        short8 Al{};
        if (!isV) Al = *reinterpret_cast<const short8*>(&wl[wid * 16 + m][quad * 8]);
        #pragma unroll
        for (int jt = 0; jt < 7; jt++) {
            const short8 Bh = *reinterpret_cast<const short8*>(&xh[jt * 16 + m][quad * 8]);
            const short8 Bl = *reinterpret_cast<const short8*>(&xl[jt * 16 + m][quad * 8]);
            acc[jt] = __builtin_amdgcn_mfma_f32_16x16x32_bf16(Ah, Bh, acc[jt], 0, 0, 0);
            acc[jt] = __builtin_amdgcn_mfma_f32_16x16x32_bf16(Ah, Bl, acc[jt], 0, 0, 0);
            if (!isV)
                acc[jt] = __builtin_amdgcn_mfma_f32_16x16x32_bf16(Al, Bh, acc[jt], 0, 0, 0);
        }
    }

    const size_t obase = (size_t)bl * CCH * NTOK;
    #pragma unroll
    for (int r = 0; r < 4; r++) {
        const int o = o0 + wid * 16 + quad * 4 + r;
        const float bi = bias[o];
        #pragma unroll
        for (int jt = 0; jt < 7; jt++) {
            const int n = n0 + jt * 16 + m;
            const float val = acc[jt][r] + bi;
            const size_t idx = obase + (size_t)o * NTOK + n;
            if (proj == 0)      Qp[idx] = packsplit(val);
            else if (proj == 1) Kp[idx] = packsplit(val);
            else                Vo[idx] = f2bf(val);
        }
    }
}

// ---------------- Flash attention: 512 thr, i-tile 128, grid (b,h,iblk) ----------------
// R14: no pt buffer; P moved Sacc-layout -> PV-B-frag-layout via pk regs +
// 16 shfl/chunk. LDS 44032 -> 3 blocks/CU.
__global__ __launch_bounds__(512, 6)
void attn_kernel(const u32* __restrict__ Qp, const u32* __restrict__ Kp,
                 const u16* __restrict__ V,
                 const float* __restrict__ rel_h, const float* __restrict__ rel_w,
                 float* __restrict__ out, int b0)
{
    const int t    = threadIdx.x;
    const int lane = t & 63;
    const int wid  = t >> 6;        // 0..7
    const int m    = lane & 15;
    const int quad = lane >> 4;
    const int bl   = blockIdx.x;
    const int h    = blockIdx.y;
    int i0 = blockIdx.z * 128;
    if (i0 > NTOK - 128) i0 = NTOK - 128;   // overlap: identical writes
    const int b  = b0 + bl;
    const int hd = h * DH;
    const size_t base  = ((size_t)bl * CCH + hd) * NTOK;
    const size_t baseo = ((size_t)b  * CCH + hd) * NTOK;

    __shared__ u16 kqh[CH][KQLD];   // 17408 B
    __shared__ u16 kql[CH][KQLD];   // 17408 B
    __shared__ u16 vt[DH][VLD];     //  9216 B  (44032 total)

    // ---- persistent queryside B-frags (wave owns i-cols i0+wid*16 .. +15)
    short8 Bh[4], Bl[4];
    {
        const int ig = i0 + wid * 16 + m;
        const int iw = ig / WSP, ih = ig % WSP;
        #pragma unroll
        for (int c = 0; c < 4; c++) {
            union { short8 v; u16 u[8]; } hb, lb;
            #pragma unroll
            for (int idx = 0; idx < 8; idx++) {
                const int k = c * 32 + quad * 8 + idx;
                if (k < DH) {
                    const u32 p = Qp[base + (size_t)k * NTOK + ig];
                    hb.u[idx] = (u16)(p & 0xFFFFu);
                    lb.u[idx] = (u16)(p >> 16);
                } else {
                    const int d = k - DH;
                    const float pos = rel_h[(size_t)(hd + d) * WSP + ih]
                                    + rel_w[(size_t)(hd + d) * WSP + iw];
                    const u32 hib = f2u(pos) & 0xFFFF0000u;
                    hb.u[idx] = (u16)(hib >> 16);
                    lb.u[idx] = f2bf(pos - u2f(hib));
                }
            }
            Bh[c] = hb.v; Bl[c] = lb.v;
        }
    }

    floatx4 Oacc[4];
    #pragma unroll
    for (int dt = 0; dt < 4; dt++) Oacc[dt] = (floatx4){0.f, 0.f, 0.f, 0.f};
    float mrun = -1e30f, lrun = 0.f;

    // staging maps (512 threads)
    const int cg4 = (t & 31) * 4;   // KQ: 4 consecutive k-rows (0..124)
    const int jb4 = (t >> 5) * 4;   // KQ: 4 j (0..60)
    const int vd  = t >> 3;         // V: d-row 0..63
    const int vj  = (t & 7) * 8;    // V: 8 j

    for (int chn = 0; chn < NCHUNK; chn++) {
        const int j0 = chn * CH;
        __syncthreads();

        // ---- stage K||Q (hi/lo planes, 4x4 transposed blocks)
        {
            u32 kv[4][4];
            #pragma unroll
            for (int cc = 0; cc < 4; cc++) {
                const int c = cg4 + cc;
                const u32* src = (c < DH) ? (Kp + base + (size_t)c * NTOK)
                                          : (Qp + base + (size_t)(c - DH) * NTOK);
                const uint4 a = *reinterpret_cast<const uint4*>(&src[j0 + jb4]);
                kv[cc][0] = a.x; kv[cc][1] = a.y; kv[cc][2] = a.z; kv[cc][3] = a.w;
            }
            #pragma unroll
            for (int jj = 0; jj < 4; jj++) {
                const ushort4 hi = make_ushort4((u16)(kv[0][jj] & 0xFFFFu), (u16)(kv[1][jj] & 0xFFFFu),
                                                (u16)(kv[2][jj] & 0xFFFFu), (u16)(kv[3][jj] & 0xFFFFu));
                const ushort4 lo = make_ushort4((u16)(kv[0][jj] >> 16), (u16)(kv[1][jj] >> 16),
                                                (u16)(kv[2][jj] >> 16), (u16)(kv[3][jj] >> 16));
                *reinterpret_cast<ushort4*>(&kqh[jb4 + jj][cg4]) = hi;
                *reinterpret_cast<ushort4*>(&kql[jb4 + jj][cg4]) = lo;
            }
        }
        // ---- stage V (zero-pad j >= NTOK)
        if (j0 + vj + 8 <= NTOK) {
            const uint4 a = *reinterpret_cast<const uint4*>(&V[base + (size_t)vd * NTOK + j0 + vj]);
            *reinterpret_cast<uint4*>(&vt[vd][vj]) = a;
        } else {
            #pragma unroll
            for (int u = 0; u < 8; u++)
                vt[vd][vj + u] = (j0 + vj + u < NTOK) ? V[base + (size_t)vd * NTOK + j0 + vj + u] : (u16)0;
        }
        __syncthreads();

        // ---- S^T tile: D[j][i]
        floatx4 Sacc[4];
        #pragma unroll
        for (int js = 0; js < 4; js++) Sacc[js] = (floatx4){0.f, 0.f, 0.f, 0.f};
        #pragma unroll
        for (int c = 0; c < 4; c++) {
            #pragma unroll
            for (int js = 0; js < 4; js++) {
                const short8 Ah = *reinterpret_cast<const short8*>(&kqh[js * 16 + m][c * 32 + quad * 8]);
                const short8 Al = *reinterpret_cast<const short8*>(&kql[js * 16 + m][c * 32 + quad * 8]);
                Sacc[js] = __builtin_amdgcn_mfma_f32_16x16x32_bf16(Ah, Bh[c], Sacc[js], 0, 0, 0);
                Sacc[js] = __builtin_amdgcn_mfma_f32_16x16x32_bf16(Ah, Bl[c], Sacc[js], 0, 0, 0);
                Sacc[js] = __builtin_amdgcn_mfma_f32_16x16x32_bf16(Al, Bh[c], Sacc[js], 0, 0, 0);
            }
        }

        // ---- online softmax (lane owns column i; rows j = js*16 + quad*4 + r)
        float sv[16];
        #pragma unroll
        for (int js = 0; js < 4; js++)
            #pragma unroll
            for (int r = 0; r < 4; r++) sv[js * 4 + r] = Sacc[js][r];
        if (j0 + CH > NTOK) {
            #pragma unroll
            for (int js = 0; js < 4; js++)
                #pragma unroll
                for (int r = 0; r < 4; r++)
                    if (j0 + js * 16 + quad * 4 + r >= NTOK) sv[js * 4 + r] = -1e30f;
        }
        float mc = sv[0];
        #pragma unroll
        for (int u = 1; u < 16; u++) mc = fmaxf(mc, sv[u]);
        mc = fmaxf(mc, __shfl_xor(mc, 16, 64));
        mc = fmaxf(mc, __shfl_xor(mc, 32, 64));
        const float mnew  = fmaxf(mrun, mc);
        const float alpha = __expf(mrun - mnew);
        float ps = 0.f;
        #pragma unroll
        for (int u = 0; u < 16; u++) {
            const float p = __expf(sv[u] - mnew);
            sv[u] = p;
            ps += p;
        }
        ps += __shfl_xor(ps, 16, 64);
        ps += __shfl_xor(ps, 32, 64);
        lrun = lrun * alpha + ps;
        mrun = mnew;
        #pragma unroll
        for (int dt = 0; dt < 4; dt++)
            #pragma unroll
            for (int r = 0; r < 4; r++) Oacc[dt][r] *= alpha;

        // ---- P -> bf16x2 pack (lane holds P[j=js*16+quad*4+r][i=m])
        u32 pk[4][2];
        #pragma unroll
        for (int js = 0; js < 4; js++) {
            pk[js][0] = ((u32)f2bf(sv[js * 4 + 1]) << 16) | f2bf(sv[js * 4 + 0]);
            pk[js][1] = ((u32)f2bf(sv[js * 4 + 3]) << 16) | f2bf(sv[js * 4 + 2]);
        }

        // ---- PV: O[d][i] += V[d][j] * P^T[j][i]; B-frag built via shfl
        #pragma unroll
        for (int joff = 0; joff < CH; joff += 32) {
            union { short8 v; u32 w[4]; } bp;
            const int jsbase = joff >> 4;   // 0 or 2
            #pragma unroll
            for (int w = 0; w < 4; w++) {
                const int srcl = m + 16 * ((quad & 1) * 2 + (w >> 1));
                const u32 v0 = __shfl(pk[jsbase + 0][w & 1], srcl, 64);
                const u32 v1 = __shfl(pk[jsbase + 1][w & 1], srcl, 64);
                bp.w[w] = (quad >> 1) ? v1 : v0;
            }
            #pragma unroll
            for (int dt = 0; dt < 4; dt++) {
                const short8 Av = *reinterpret_cast<const short8*>(&vt[dt * 16 + m][joff + quad * 8]);
                Oacc[dt] = __builtin_amdgcn_mfma_f32_16x16x32_bf16(Av, bp.v, Oacc[dt], 0, 0, 0);
            }
        }
    }

    // ---- epilogue
    const float linv = 1.f / lrun;
    #pragma unroll
    for (int dt = 0; dt < 4; dt++) {
        #pragma unroll
        for (int r = 0; r < 4; r++) {
            const int d = dt * 16 + quad * 4 + r;
            out[baseo + (size_t)d * NTOK + i0 + wid * 16 + m] = Oacc[dt][r] * linv;
        }
    }
}

extern "C" void kernel_launch(void* const* d_in, const int* in_sizes, int n_in,
                              void* d_out, int out_size, void* d_ws, size_t ws_size,
                              hipStream_t stream)
{
    const float* x  = (const float*)d_in[0];
    const float* wq = (const float*)d_in[1];
    const float* bq = (const float*)d_in[2];
    const float* wk = (const float*)d_in[3];
    const float* bk = (const float*)d_in[4];
    const float* wv = (const float*)d_in[5];
    const float* bv = (const float*)d_in[6];
    const float* rh = (const float*)d_in[7];
    const float* rw = (const float*)d_in[8];
    float* out = (float*)d_out;

    const size_t perB = (size_t)CCH * NTOK;
    const size_t WELEM = (size_t)CCH * CCH;
    const size_t weightBytes = 3 * WELEM * 4;
    const size_t perBatchBytes = perB * 14;   // Xt u32 + Qp u32 + Kp u32 + V u16

    size_t avail = (ws_size > weightBytes) ? (ws_size - weightBytes) : perBatchBytes;
    size_t nb_s = avail / perBatchBytes;
    int nb = (int)(nb_s < 1 ? 1 : (nb_s > BATCH ? BATCH : nb_s));

    u32* Wqp = (u32*)d_ws;
    u32* Wkp = Wqp + WELEM;
    u32* Wvp = Wkp + WELEM;
    u32* chunk0 = Wvp + WELEM;

    pack_weights<<<dim3((CCH * CCH + 255) / 256), dim3(256), 0, stream>>>(wq, wk, wv, Wqp, Wkp, Wvp);

    for (int b0 = 0; b0 < BATCH; b0 += nb) {
        const int curb = (BATCH - b0 < nb) ? (BATCH - b0) : nb;
        u32* Xt = chunk0;
        u32* Qp = Xt + (size_t)curb * perB;
        u32* Kp = Qp + (size_t)curb * perB;
        u16* Vb = (u16*)(Kp + (size_t)curb * perB);

        dim3 gx((NTOK + 31) / 32, CCH / 32, curb);   // 25 x 16 x curb
        pack_xt<<<gx, dim3(256), 0, stream>>>(x, Xt, b0);

        dim3 gp(NTOK / NT, CCH / OT, 3 * curb);   // 7 x 4 x 3*curb
        qkv_proj<<<gp, dim3(512), 0, stream>>>(Xt, Wqp, bq, Wkp, bk, Wvp, bv,
                                               Qp, Kp, Vb, curb);

        dim3 ga(curb, NHEAD, NIBLK);   // (b, h, iblk): same-(b,h) -> same XCD
        attn_kernel<<<ga, dim3(512), 0, stream>>>(Qp, Kp, Vb, rh, rw, out, b0);
    }
}

// Round 8
// 494.433 us; speedup vs baseline: 1.3563x; 1.3563x over previous
//
#include <hip/hip_runtime.h>

// MHSA: B=32, C=512, HEADS=8, d=64, N=784. fp32 in/out.
// Round 16 == Round 15 resubmitted (R15 bench died to container infra).
//  - attn: exact R13/R8 revert (R14: launch_bounds(512,6) caps unified
//    VGPR+AGPR at ~85 < live-set ~110 -> 70-reg spill, FETCH 3.3x. 3 blocks/CU
//    is unreachable for this structure; pt-shfl is LDS-pipe-neutral. Closed.)
//  - proj: n-tile 112 -> 160 (5 blocks, one clamped; 2% overlap waste).
//    1.4x fewer serial block-slots/CU, 1.43x more MFMA per barrier pair.
//    acc[7]->acc[10] (~90 total regs, safe under 128 2-block cliff).
//  - proj V 2-product + pack_xt transpose kept from R13 (passed, 512.3us).

#define BATCH 32
#define CCH   512
#define NHEAD 8
#define DH    64
#define NTOK  784
#define WSP   28
#define OT    128    // proj o-tile
#define NT    160    // proj n-tile (5 blocks, last clamped to 624)
#define NXB   5      // proj x-blocks
#define NJT   10     // NT/16
#define WLD   40     // proj LDS row stride (u16)
#define CH    64     // attn j-chunk
#define NCHUNK 13
#define NIBLK  7     // ceil(784/128)
#define KQLD  136    // 128 + 8 pad (16B-mult)
#define VLD   72     // 64 + 8 pad (16B-mult)

typedef unsigned short u16;
typedef unsigned int   u32;
typedef short  short8  __attribute__((ext_vector_type(8)));
typedef float  floatx4 __attribute__((ext_vector_type(4)));

__device__ __forceinline__ u16 f2bf(float f) {
    union { float f; u32 i; } v; v.f = f;
    u32 x = v.i;
    return (u16)((x + 0x7FFFu + ((x >> 16) & 1u)) >> 16);
}
__device__ __forceinline__ u32 f2u(float f) { union { float f; u32 i; } v; v.f = f; return v.i; }
__device__ __forceinline__ float u2f(u32 u) { union { u32 i; float f; } v; v.i = u; return v.f; }

__device__ __forceinline__ u32 packsplit(float f) {
    const u32 hib = f2u(f) & 0xFFFF0000u;
    const float lo = f - u2f(hib);
    return ((u32)f2bf(lo) << 16) | (hib >> 16);
}

// ---------------- prepack: weights ----------------
__global__ __launch_bounds__(256)
void pack_weights(const float* __restrict__ wq, const float* __restrict__ wk,
                  const float* __restrict__ wv,
                  u32* __restrict__ Wqp, u32* __restrict__ Wkp, u32* __restrict__ Wvp)
{
    const int i = blockIdx.x * 256 + threadIdx.x;
    if (i < CCH * CCH) {
        Wqp[i] = packsplit(wq[i]);
        Wkp[i] = packsplit(wk[i]);
        Wvp[i] = packsplit(wv[i]);
    }
}

// ---------------- prepack: x transpose -> Xt[b][n][c] (packed hi|lo) ----------------
__global__ __launch_bounds__(256)
void pack_xt(const float* __restrict__ x, u32* __restrict__ Xt, int b0)
{
    const int bl = blockIdx.z;
    const int c0 = blockIdx.y * 32;
    const int n0 = blockIdx.x * 32;
    const int t  = threadIdx.x;
    const int tn = t & 31;          // 0..31
    const int tr = t >> 5;          // 0..7

    __shared__ float tile[32][33];

    const size_t xb = (size_t)(b0 + bl) * CCH * NTOK;
    #pragma unroll
    for (int k = 0; k < 4; k++) {
        const int c = tr + k * 8;                 // 0..31
        const int n = n0 + tn;
        if (n < NTOK)
            tile[c][tn] = x[xb + (size_t)(c0 + c) * NTOK + n];
    }
    __syncthreads();
    const size_t ob = (size_t)bl * NTOK * CCH;
    #pragma unroll
    for (int k = 0; k < 4; k++) {
        const int n = n0 + tr + k * 8;
        const int c = c0 + tn;
        if (n < NTOK)
            Xt[ob + (size_t)n * CCH + c] = packsplit(tile[tn][tr + k * 8]);
    }
}

// ---------------- MFMA QKV projection: 512 thr, o-tile 128 x n-tile 160 ----------------
// X pre-transposed [n][c]; rotated staging; V blocks: 2-product emulation.
__global__ __launch_bounds__(512, 4)
void qkv_proj(const u32* __restrict__ Xt,
              const u32* __restrict__ Wqp, const float* __restrict__ bq,
              const u32* __restrict__ Wkp, const float* __restrict__ bk,
              const u32* __restrict__ Wvp, const float* __restrict__ bv,
              u32* __restrict__ Qp, u32* __restrict__ Kp, u16* __restrict__ Vo,
              int nbatch)
{
    const int t    = threadIdx.x;
    const int lane = t & 63;
    const int wid  = t >> 6;        // 0..7
    const int z    = blockIdx.z;
    const int proj = z / nbatch;
    const int bl   = z - proj * nbatch;
    const int o0   = blockIdx.y * OT;     // y in 0..3
    int n0 = blockIdx.x * NT;             // x in 0..4
    if (n0 > NTOK - NT) n0 = NTOK - NT;   // clamp: overlap writes identical values

    const u32*   Wp   = (proj == 0) ? Wqp : (proj == 1) ? Wkp : Wvp;
    const float* bias = (proj == 0) ? bq  : (proj == 1) ? bk  : bv;
    const bool   isV  = (proj == 2);      // block-uniform

    __shared__ u16 wh[OT][WLD], wl[OT][WLD];   // 2 x 10240 B
    __shared__ u16 xh[NT][WLD], xl[NT][WLD];   // 2 x 12800 B  (46080 total)

    const int m    = lane & 15;
    const int quad = lane >> 4;

    floatx4 acc[NJT];
    #pragma unroll
    for (int j = 0; j < NJT; j++) acc[j] = (floatx4){0.f, 0.f, 0.f, 0.f};

    // staging maps: W by all 512 (128 rows x 8 u32);
    // X rows 0..127 by all 512 (2x uint4), rows 128..159 by t<128 (2x uint4)
    const int wo = t >> 2;           // 0..127
    const int wc = (t & 3) * 8;      // 0,8,16,24
    const int xrow = t >> 2;         // 0..127
    const int xc8  = (t & 3) * 8;    // 0,8,16,24
    const int xrow2 = 128 + (t >> 2);   // 128..159 (t<128)

    const size_t xtbase = (size_t)bl * NTOK * CCH;

    // ---- prologue: load K-step 0 into regs
    uint4 wv0, wv1, xv0, xv1, xv2, xv3;
    {
        wv0 = *reinterpret_cast<const uint4*>(&Wp[(size_t)(o0 + wo) * CCH + 0 + wc]);
        wv1 = *reinterpret_cast<const uint4*>(&Wp[(size_t)(o0 + wo) * CCH + 0 + wc + 4]);
        xv0 = *reinterpret_cast<const uint4*>(&Xt[xtbase + (size_t)(n0 + xrow) * CCH + 0 + xc8]);
        xv1 = *reinterpret_cast<const uint4*>(&Xt[xtbase + (size_t)(n0 + xrow) * CCH + 0 + xc8 + 4]);
        if (t < 128) {
            xv2 = *reinterpret_cast<const uint4*>(&Xt[xtbase + (size_t)(n0 + xrow2) * CCH + 0 + xc8]);
            xv3 = *reinterpret_cast<const uint4*>(&Xt[xtbase + (size_t)(n0 + xrow2) * CCH + 0 + xc8 + 4]);
        }
    }

    for (int c0 = 0; c0 < CCH; c0 += 32) {
        __syncthreads();   // release: prev compute done
        {
            const u32 wr[8] = {wv0.x, wv0.y, wv0.z, wv0.w, wv1.x, wv1.y, wv1.z, wv1.w};
            ushort4 h0 = make_ushort4((u16)(wr[0] & 0xFFFF), (u16)(wr[1] & 0xFFFF), (u16)(wr[2] & 0xFFFF), (u16)(wr[3] & 0xFFFF));
            ushort4 h1 = make_ushort4((u16)(wr[4] & 0xFFFF), (u16)(wr[5] & 0xFFFF), (u16)(wr[6] & 0xFFFF), (u16)(wr[7] & 0xFFFF));
            *reinterpret_cast<ushort4*>(&wh[wo][wc])     = h0;
            *reinterpret_cast<ushort4*>(&wh[wo][wc + 4]) = h1;
            if (!isV) {
                ushort4 l0 = make_ushort4((u16)(wr[0] >> 16), (u16)(wr[1] >> 16), (u16)(wr[2] >> 16), (u16)(wr[3] >> 16));
                ushort4 l1 = make_ushort4((u16)(wr[4] >> 16), (u16)(wr[5] >> 16), (u16)(wr[6] >> 16), (u16)(wr[7] >> 16));
                *reinterpret_cast<ushort4*>(&wl[wo][wc])     = l0;
                *reinterpret_cast<ushort4*>(&wl[wo][wc + 4]) = l1;
            }
        }
        {
            const u32 xr[8] = {xv0.x, xv0.y, xv0.z, xv0.w, xv1.x, xv1.y, xv1.z, xv1.w};
            ushort4 h0 = make_ushort4((u16)(xr[0] & 0xFFFF), (u16)(xr[1] & 0xFFFF), (u16)(xr[2] & 0xFFFF), (u16)(xr[3] & 0xFFFF));
            ushort4 h1 = make_ushort4((u16)(xr[4] & 0xFFFF), (u16)(xr[5] & 0xFFFF), (u16)(xr[6] & 0xFFFF), (u16)(xr[7] & 0xFFFF));
            ushort4 l0 = make_ushort4((u16)(xr[0] >> 16), (u16)(xr[1] >> 16), (u16)(xr[2] >> 16), (u16)(xr[3] >> 16));
            ushort4 l1 = make_ushort4((u16)(xr[4] >> 16), (u16)(xr[5] >> 16), (u16)(xr[6] >> 16), (u16)(xr[7] >> 16));
            *reinterpret_cast<ushort4*>(&xh[xrow][xc8])     = h0;
            *reinterpret_cast<ushort4*>(&xh[xrow][xc8 + 4]) = h1;
            *reinterpret_cast<ushort4*>(&xl[xrow][xc8])     = l0;
            *reinterpret_cast<ushort4*>(&xl[xrow][xc8 + 4]) = l1;
        }
        if (t < 128) {
            const u32 xr[8] = {xv2.x, xv2.y, xv2.z, xv2.w, xv3.x, xv3.y, xv3.z, xv3.w};
            ushort4 h0 = make_ushort4((u16)(xr[0] & 0xFFFF), (u16)(xr[1] & 0xFFFF), (u16)(xr[2] & 0xFFFF), (u16)(xr[3] & 0xFFFF));
            ushort4 h1 = make_ushort4((u16)(xr[4] & 0xFFFF), (u16)(xr[5] & 0xFFFF), (u16)(xr[6] & 0xFFFF), (u16)(xr[7] & 0xFFFF));
            ushort4 l0 = make_ushort4((u16)(xr[0] >> 16), (u16)(xr[1] >> 16), (u16)(xr[2] >> 16), (u16)(xr[3] >> 16));
            ushort4 l1 = make_ushort4((u16)(xr[4] >> 16), (u16)(xr[5] >> 16), (u16)(xr[6] >> 16), (u16)(xr[7] >> 16));
            *reinterpret_cast<ushort4*>(&xh[xrow2][xc8])     = h0;
            *reinterpret_cast<ushort4*>(&xh[xrow2][xc8 + 4]) = h1;
            *reinterpret_cast<ushort4*>(&xl[xrow2][xc8])     = l0;
            *reinterpret_cast<ushort4*>(&xl[xrow2][xc8 + 4]) = l1;
        }
        __syncthreads();   // publish

        // ---- prefetch next K-step; consumed next iteration
        if (c0 + 32 < CCH) {
            wv0 = *reinterpret_cast<const uint4*>(&Wp[(size_t)(o0 + wo) * CCH + c0 + 32 + wc]);
            wv1 = *reinterpret_cast<const uint4*>(&Wp[(size_t)(o0 + wo) * CCH + c0 + 32 + wc + 4]);
            xv0 = *reinterpret_cast<const uint4*>(&Xt[xtbase + (size_t)(n0 + xrow) * CCH + c0 + 32 + xc8]);
            xv1 = *reinterpret_cast<const uint4*>(&Xt[xtbase + (size_t)(n0 + xrow) * CCH + c0 + 32 + xc8 + 4]);
            if (t < 128) {
                xv2 = *reinterpret_cast<const uint4*>(&Xt[xtbase + (size_t)(n0 + xrow2) * CCH + c0 + 32 + xc8]);
                xv3 = *reinterpret_cast<const uint4*>(&Xt[xtbase + (size_t)(n0 + xrow2) * CCH + c0 + 32 + xc8 + 4]);
            }
        }
        __builtin_amdgcn_sched_barrier(0);   // keep load issue ahead of compute

        const short8 Ah = *reinterpret_cast<const short8*>(&wh[wid * 16 + m][quad * 8]);
        short8 Al{};
        if (!isV) Al = *reinterpret_cast<const short8*>(&wl[wid * 16 + m][quad * 8]);
        #pragma unroll
        for (int jt = 0; jt < NJT; jt++) {
            const short8 Bh = *reinterpret_cast<const short8*>(&xh[jt * 16 + m][quad * 8]);
            const short8 Bl = *reinterpret_cast<const short8*>(&xl[jt * 16 + m][quad * 8]);
            acc[jt] = __builtin_amdgcn_mfma_f32_16x16x32_bf16(Ah, Bh, acc[jt], 0, 0, 0);
            acc[jt] = __builtin_amdgcn_mfma_f32_16x16x32_bf16(Ah, Bl, acc[jt], 0, 0, 0);
            if (!isV)
                acc[jt] = __builtin_amdgcn_mfma_f32_16x16x32_bf16(Al, Bh, acc[jt], 0, 0, 0);
        }
    }

    const size_t obase = (size_t)bl * CCH * NTOK;
    #pragma unroll
    for (int r = 0; r < 4; r++) {
        const int o = o0 + wid * 16 + quad * 4 + r;
        const float bi = bias[o];
        #pragma unroll
        for (int jt = 0; jt < NJT; jt++) {
            const int n = n0 + jt * 16 + m;
            const float val = acc[jt][r] + bi;
            const size_t idx = obase + (size_t)o * NTOK + n;
            if (proj == 0)      Qp[idx] = packsplit(val);
            else if (proj == 1) Kp[idx] = packsplit(val);
            else                Vo[idx] = f2bf(val);
        }
    }
}

// ---------------- Flash attention: 512 thr, i-tile 128, grid (b,h,iblk) ----------------
// Exact R8/R13 structure (276 us, VGPR 60, 2 blocks/CU).
__global__ __launch_bounds__(512)
void attn_kernel(const u32* __restrict__ Qp, const u32* __restrict__ Kp,
                 const u16* __restrict__ V,
                 const float* __restrict__ rel_h, const float* __restrict__ rel_w,
                 float* __restrict__ out, int b0)
{
    const int t    = threadIdx.x;
    const int lane = t & 63;
    const int wid  = t >> 6;        // 0..7
    const int m    = lane & 15;
    const int quad = lane >> 4;
    const int bl   = blockIdx.x;
    const int h    = blockIdx.y;
    int i0 = blockIdx.z * 128;
    if (i0 > NTOK - 128) i0 = NTOK - 128;   // overlap: identical writes
    const int b  = b0 + bl;
    const int hd = h * DH;
    const size_t base  = ((size_t)bl * CCH + hd) * NTOK;
    const size_t baseo = ((size_t)b  * CCH + hd) * NTOK;

    __shared__ u16 kqh[CH][KQLD];   // 17408 B
    __shared__ u16 kql[CH][KQLD];   // 17408 B
    __shared__ u16 vt[DH][VLD];     //  9216 B
    __shared__ u16 pt[128][VLD];    // 18432 B  (62464 total)

    // ---- persistent queryside B-frags (wave owns i-cols i0+wid*16 .. +15)
    short8 Bh[4], Bl[4];
    {
        const int ig = i0 + wid * 16 + m;
        const int iw = ig / WSP, ih = ig % WSP;
        #pragma unroll
        for (int c = 0; c < 4; c++) {
            union { short8 v; u16 u[8]; } hb, lb;
            #pragma unroll
            for (int idx = 0; idx < 8; idx++) {
                const int k = c * 32 + quad * 8 + idx;
                if (k < DH) {
                    const u32 p = Qp[base + (size_t)k * NTOK + ig];
                    hb.u[idx] = (u16)(p & 0xFFFFu);
                    lb.u[idx] = (u16)(p >> 16);
                } else {
                    const int d = k - DH;
                    const float pos = rel_h[(size_t)(hd + d) * WSP + ih]
                                    + rel_w[(size_t)(hd + d) * WSP + iw];
                    const u32 hib = f2u(pos) & 0xFFFF0000u;
                    hb.u[idx] = (u16)(hib >> 16);
                    lb.u[idx] = f2bf(pos - u2f(hib));
                }
            }
            Bh[c] = hb.v; Bl[c] = lb.v;
        }
    }

    floatx4 Oacc[4];
    #pragma unroll
    for (int dt = 0; dt < 4; dt++) Oacc[dt] = (floatx4){0.f, 0.f, 0.f, 0.f};
    float mrun = -1e30f, lrun = 0.f;

    // staging maps (512 threads)
    const int cg4 = (t & 31) * 4;   // KQ: 4 consecutive k-rows (0..124)
    const int jb4 = (t >> 5) * 4;   // KQ: 4 j (0..60)
    const int vd  = t >> 3;         // V: d-row 0..63
    const int vj  = (t & 7) * 8;    // V: 8 j

    for (int chn = 0; chn < NCHUNK; chn++) {
        const int j0 = chn * CH;
        __syncthreads();

        // ---- stage K||Q (hi/lo planes, 4x4 transposed blocks)
        {
            u32 kv[4][4];
            #pragma unroll
            for (int cc = 0; cc < 4; cc++) {
                const int c = cg4 + cc;
                const u32* src = (c < DH) ? (Kp + base + (size_t)c * NTOK)
                                          : (Qp + base + (size_t)(c - DH) * NTOK);
                const uint4 a = *reinterpret_cast<const uint4*>(&src[j0 + jb4]);
                kv[cc][0] = a.x; kv[cc][1] = a.y; kv[cc][2] = a.z; kv[cc][3] = a.w;
            }
            #pragma unroll
            for (int jj = 0; jj < 4; jj++) {
                const ushort4 hi = make_ushort4((u16)(kv[0][jj] & 0xFFFFu), (u16)(kv[1][jj] & 0xFFFFu),
                                                (u16)(kv[2][jj] & 0xFFFFu), (u16)(kv[3][jj] & 0xFFFFu));
                const ushort4 lo = make_ushort4((u16)(kv[0][jj] >> 16), (u16)(kv[1][jj] >> 16),
                                                (u16)(kv[2][jj] >> 16), (u16)(kv[3][jj] >> 16));
                *reinterpret_cast<ushort4*>(&kqh[jb4 + jj][cg4]) = hi;
                *reinterpret_cast<ushort4*>(&kql[jb4 + jj][cg4]) = lo;
            }
        }
        // ---- stage V (zero-pad j >= NTOK)
        if (j0 + vj + 8 <= NTOK) {
            const uint4 a = *reinterpret_cast<const uint4*>(&V[base + (size_t)vd * NTOK + j0 + vj]);
            *reinterpret_cast<uint4*>(&vt[vd][vj]) = a;
        } else {
            #pragma unroll
            for (int u = 0; u < 8; u++)
                vt[vd][vj + u] = (j0 + vj + u < NTOK) ? V[base + (size_t)vd * NTOK + j0 + vj + u] : (u16)0;
        }
        __syncthreads();

        // ---- S^T tile: D[j][i]
        floatx4 Sacc[4];
        #pragma unroll
        for (int js = 0; js < 4; js++) Sacc[js] = (floatx4){0.f, 0.f, 0.f, 0.f};
        #pragma unroll
        for (int c = 0; c < 4; c++) {
            #pragma unroll
            for (int js = 0; js < 4; js++) {
                const short8 Ah = *reinterpret_cast<const short8*>(&kqh[js * 16 + m][c * 32 + quad * 8]);
                const short8 Al = *reinterpret_cast<const short8*>(&kql[js * 16 + m][c * 32 + quad * 8]);
                Sacc[js] = __builtin_amdgcn_mfma_f32_16x16x32_bf16(Ah, Bh[c], Sacc[js], 0, 0, 0);
                Sacc[js] = __builtin_amdgcn_mfma_f32_16x16x32_bf16(Ah, Bl[c], Sacc[js], 0, 0, 0);
                Sacc[js] = __builtin_amdgcn_mfma_f32_16x16x32_bf16(Al, Bh[c], Sacc[js], 0, 0, 0);
            }
        }

        // ---- online softmax (lane owns column i; rows j = js*16 + quad*4 + r)
        float sv[16];
        #pragma unroll
        for (int js = 0; js < 4; js++)
            #pragma unroll
            for (int r = 0; r < 4; r++) sv[js * 4 + r] = Sacc[js][r];
        if (j0 + CH > NTOK) {
            #pragma unroll
            for (int js = 0; js < 4; js++)
                #pragma unroll
                for (int r = 0; r < 4; r++)
                    if (j0 + js * 16 + quad * 4 + r >= NTOK) sv[js * 4 + r] = -1e30f;
        }
        float mc = sv[0];
        #pragma unroll
        for (int u = 1; u < 16; u++) mc = fmaxf(mc, sv[u]);
        mc = fmaxf(mc, __shfl_xor(mc, 16, 64));
        mc = fmaxf(mc, __shfl_xor(mc, 32, 64));
        const float mnew  = fmaxf(mrun, mc);
        const float alpha = __expf(mrun - mnew);
        float ps = 0.f;
        #pragma unroll
        for (int u = 0; u < 16; u++) {
            const float p = __expf(sv[u] - mnew);
            sv[u] = p;
            ps += p;
        }
        ps += __shfl_xor(ps, 16, 64);
        ps += __shfl_xor(ps, 32, 64);
        lrun = lrun * alpha + ps;
        mrun = mnew;
        #pragma unroll
        for (int dt = 0; dt < 4; dt++)
            #pragma unroll
            for (int r = 0; r < 4; r++) Oacc[dt][r] *= alpha;

        // ---- P^T -> wave-local LDS tile [i][j]
        #pragma unroll
        for (int js = 0; js < 4; js++) {
            const ushort4 pw = make_ushort4(f2bf(sv[js * 4 + 0]), f2bf(sv[js * 4 + 1]),
                                            f2bf(sv[js * 4 + 2]), f2bf(sv[js * 4 + 3]));
            *reinterpret_cast<ushort4*>(&pt[wid * 16 + m][js * 16 + quad * 4]) = pw;
        }

        // ---- PV: O[d][i] += V[d][j] * P^T[j][i]
        #pragma unroll
        for (int joff = 0; joff < CH; joff += 32) {
            const short8 Bp = *reinterpret_cast<const short8*>(&pt[wid * 16 + m][joff + quad * 8]);
            #pragma unroll
            for (int dt = 0; dt < 4; dt++) {
                const short8 Av = *reinterpret_cast<const short8*>(&vt[dt * 16 + m][joff + quad * 8]);
                Oacc[dt] = __builtin_amdgcn_mfma_f32_16x16x32_bf16(Av, Bp, Oacc[dt], 0, 0, 0);
            }
        }
    }

    // ---- epilogue
    const float linv = 1.f / lrun;
    #pragma unroll
    for (int dt = 0; dt < 4; dt++) {
        #pragma unroll
        for (int r = 0; r < 4; r++) {
            const int d = dt * 16 + quad * 4 + r;
            out[baseo + (size_t)d * NTOK + i0 + wid * 16 + m] = Oacc[dt][r] * linv;
        }
    }
}

extern "C" void kernel_launch(void* const* d_in, const int* in_sizes, int n_in,
                              void* d_out, int out_size, void* d_ws, size_t ws_size,
                              hipStream_t stream)
{
    const float* x  = (const float*)d_in[0];
    const float* wq = (const float*)d_in[1];
    const float* bq = (const float*)d_in[2];
    const float* wk = (const float*)d_in[3];
    const float* bk = (const float*)d_in[4];
    const float* wv = (const float*)d_in[5];
    const float* bv = (const float*)d_in[6];
    const float* rh = (const float*)d_in[7];
    const float* rw = (const float*)d_in[8];
    float* out = (float*)d_out;

    const size_t perB = (size_t)CCH * NTOK;
    const size_t WELEM = (size_t)CCH * CCH;
    const size_t weightBytes = 3 * WELEM * 4;
    const size_t perBatchBytes = perB * 14;   // Xt u32 + Qp u32 + Kp u32 + V u16

    size_t avail = (ws_size > weightBytes) ? (ws_size - weightBytes) : perBatchBytes;
    size_t nb_s = avail / perBatchBytes;
    int nb = (int)(nb_s < 1 ? 1 : (nb_s > BATCH ? BATCH : nb_s));

    u32* Wqp = (u32*)d_ws;
    u32* Wkp = Wqp + WELEM;
    u32* Wvp = Wkp + WELEM;
    u32* chunk0 = Wvp + WELEM;

    pack_weights<<<dim3((CCH * CCH + 255) / 256), dim3(256), 0, stream>>>(wq, wk, wv, Wqp, Wkp, Wvp);

    for (int b0 = 0; b0 < BATCH; b0 += nb) {
        const int curb = (BATCH - b0 < nb) ? (BATCH - b0) : nb;
        u32* Xt = chunk0;
        u32* Qp = Xt + (size_t)curb * perB;
        u32* Kp = Qp + (size_t)curb * perB;
        u16* Vb = (u16*)(Kp + (size_t)curb * perB);

        dim3 gx((NTOK + 31) / 32, CCH / 32, curb);   // 25 x 16 x curb
        pack_xt<<<gx, dim3(256), 0, stream>>>(x, Xt, b0);

        dim3 gp(NXB, CCH / OT, 3 * curb);   // 5 x 4 x 3*curb
        qkv_proj<<<gp, dim3(512), 0, stream>>>(Xt, Wqp, bq, Wkp, bk, Wvp, bv,
                                               Qp, Kp, Vb, curb);

        dim3 ga(curb, NHEAD, NIBLK);   // (b, h, iblk): same-(b,h) -> same XCD
        attn_kernel<<<ga, dim3(512), 0, stream>>>(Qp, Kp, Vb, rh, rw, out, b0);
    }
}